// Round 4
// baseline (373.439 us; speedup 1.0000x reference)
//
#include <hip/hip_runtime.h>
#include <hip/hip_fp16.h>
#include <cmath>

// Problem constants: B=8, S=1024, HID=1024, HEADS=16, HEAD_DIM=64
// M = B*S = 8192 rows for every GEMM; N = K = 1024.

typedef _Float16 f16;
typedef __attribute__((ext_vector_type(4))) _Float16 f16x4;
typedef __attribute__((ext_vector_type(8))) _Float16 f16x8;
typedef __attribute__((ext_vector_type(4))) float f32x4;

#define MFMA16(a, b, c) __builtin_amdgcn_mfma_f32_16x16x32_f16((a), (b), (c), 0, 0, 0)
#define MFMA16K16(a, b, c) __builtin_amdgcn_mfma_f32_16x16x16f16((a), (b), (c), 0, 0, 0)

// Async global->LDS, 16B per lane. LDS dest is wave-uniform base + lane*16.
__device__ __forceinline__ void g2l16(void* lds, const void* g) {
  __builtin_amdgcn_global_load_lds(
      (const __attribute__((address_space(1))) void*)g,
      (__attribute__((address_space(3))) void*)lds,
      16, 0, 0);
}

// ---------------- fp32 -> fp16 weight conversion ----------------
__global__ void cvt4_kernel(const float* __restrict__ a, const float* __restrict__ b,
                            const float* __restrict__ c, const float* __restrict__ d,
                            f16* __restrict__ oa, f16* __restrict__ ob,
                            f16* __restrict__ oc, f16* __restrict__ od) {
  const float* src;
  f16* dst;
  if (blockIdx.y == 0) { src = a; dst = oa; }
  else if (blockIdx.y == 1) { src = b; dst = ob; }
  else if (blockIdx.y == 2) { src = c; dst = oc; }
  else { src = d; dst = od; }
  size_t t = (size_t)blockIdx.x * 256 + threadIdx.x;
  float4 v = ((const float4*)src)[t];
  f16x4 w = { (f16)v.x, (f16)v.y, (f16)v.z, (f16)v.w };
  ((f16x4*)dst)[t] = w;
}

// ---------------- GEMM: Out[M,N] = A[M,K] * W[N,K]^T + bias, fp16 MFMA ----------------
// 128x128 tile, BK=64, 4 waves (2x2 of 64x64). XCD-aware swizzle: flat%8 picks an
// m-slab (8 m-tiles), so each XCD's L2 holds a 2-4 MB A slab + the 2 MB weight and A is
// fetched ~once from HBM instead of 8x (R3: FETCH was 200 MB vs 54 MB unique).
// A_FP32: A staged from fp32 with in-register RNE convert (fuses the old cvt3 kernel);
// B always via global_load_lds + XOR chunk swizzle.
struct GemmBatch {
  const void* A[3];
  const f16* W[3];
  const float* bias[3];
  void* O[3];
};

template <bool A_FP32, bool OUT_F16>
__global__ __launch_bounds__(256)
void gemm_f16_kernel(GemmBatch gb) {
  __shared__ __align__(16) f16 sA[128 * 64];
  __shared__ __align__(16) f16 sB[128 * 64];
  const int z = blockIdx.z;
  const void* __restrict__ Araw = gb.A[z];
  const f16* __restrict__ Bw = gb.W[z];
  const float* __restrict__ bias = gb.bias[z];
  void* __restrict__ Out = gb.O[z];

  const int tid = threadIdx.x;
  const int lane = tid & 63;
  const int wv = tid >> 6;
  const int l15 = lane & 15;
  const int quad = lane >> 4;

  // XCD swizzle: grid (8,64,z); flat%8 = XCD (dispatch round-robin heuristic).
  const int flat = blockIdx.x + (blockIdx.y << 3);
  const int xcd = flat & 7;
  const int t64 = flat >> 3;               // 0..63
  const int m0 = (xcd * 8 + (t64 & 7)) * 128;
  const int n0 = (t64 >> 3) * 128;

  const int wm = (wv & 1) * 64;
  const int wn = (wv >> 1) * 64;

  // B staging (async): lane -> row octet (lane>>3), chunk (lane&7)^(lane>>3).
  const int srow = lane >> 3;
  const int schunk = (lane & 7) ^ srow;
  const f16* gB = Bw + (size_t)(n0 + wv * 32 + srow) * 1024 + schunk * 8;
  f16* lB = sB + (wv * 32) * 64;

  // A staging, fp16 path (async, same pattern as B):
  const f16* gA16 = (const f16*)Araw + (size_t)(m0 + wv * 32 + srow) * 1024 + schunk * 8;
  f16* lA = sA + (wv * 32) * 64;
  // A staging, fp32 path: 16-lane groups; lane (g = lane>>4, i = lane&15) owns
  // row_local = g*8 + (i>>1), float-half kh = (i&1)*32. Within a 16-lane group the
  // 8 slot values are each hit by exactly 2 lanes (2-way = free).
  const int gi = lane >> 4, ii = lane & 15;
  const int rowl = gi * 8 + (ii >> 1);     // 0..31
  const int kh = (ii & 1) * 32;            // float offset within 64-wide k-slice
  const float* gA32 = (const float*)Araw + (size_t)(m0 + wv * 32 + rowl) * 1024 + kh;
  f16* sAw = sA + (size_t)(wv * 32 + rowl) * 64;

  f32x4 acc[4][4] = {};

  for (int k0 = 0; k0 < 1024; k0 += 64) {
    __syncthreads();  // previous iter's LDS reads complete before overwrite
#pragma unroll
    for (int j = 0; j < 4; ++j)
      g2l16(lB + j * 8 * 64, gB + (size_t)j * 8 * 1024 + k0);
    if constexpr (A_FP32) {
#pragma unroll
      for (int half = 0; half < 2; ++half) {
        float4 va[4];
#pragma unroll
        for (int j = 0; j < 4; ++j)
          va[j] = *(const float4*)(gA32 + k0 + half * 16 + j * 4);
        const float* vf = (const float*)va;
#pragma unroll
        for (int c = 0; c < 2; ++c) {
          f16x8 w;
#pragma unroll
          for (int e = 0; e < 8; ++e) w[e] = (f16)vf[c * 8 + e];
          const int ch = (ii & 1) * 4 + half * 2 + c;
          *(f16x8*)(sAw + ((ch ^ (rowl & 7)) * 8)) = w;
        }
      }
    } else {
#pragma unroll
      for (int j = 0; j < 4; ++j)
        g2l16(lA + j * 8 * 64, gA16 + (size_t)j * 8 * 1024 + k0);
    }
    __syncthreads();  // staging drained
#pragma unroll
    for (int kc = 0; kc < 2; ++kc) {
      f16x8 af[4], bf[4];
#pragma unroll
      for (int t = 0; t < 4; ++t) {
        const int swz = ((kc * 4 + quad) ^ (l15 & 7)) * 8;
        af[t] = *(const f16x8*)(sA + (wm + t * 16 + l15) * 64 + swz);
        bf[t] = *(const f16x8*)(sB + (wn + t * 16 + l15) * 64 + swz);
      }
#pragma unroll
      for (int mi = 0; mi < 4; ++mi)
#pragma unroll
        for (int ni = 0; ni < 4; ++ni)
          acc[mi][ni] = MFMA16(af[mi], bf[ni], acc[mi][ni]);
    }
  }

  // Epilogue. C/D layout: row = quad*4 + r, col = lane&15 (per 16x16 tile).
#pragma unroll
  for (int ni = 0; ni < 4; ++ni) {
    const int col = n0 + wn + ni * 16 + l15;
    const float bv = bias[col];
#pragma unroll
    for (int mi = 0; mi < 4; ++mi) {
      const int row0 = m0 + wm + mi * 16 + quad * 4;
#pragma unroll
      for (int r = 0; r < 4; ++r) {
        float v = acc[mi][ni][r] + bv;
        if (OUT_F16)
          ((f16*)Out)[(size_t)(row0 + r) * 1024 + col] = (f16)v;
        else
          ((float*)Out)[(size_t)(row0 + r) * 1024 + col] = v;
      }
    }
  }
}

// ---------------- RoPE v2: fully coalesced, Vt transpose through LDS ----------------
__global__ __launch_bounds__(256)
void rope_kernel(f16* __restrict__ q, f16* __restrict__ k,
                 const f16* __restrict__ v, f16* __restrict__ vt) {
  __shared__ f16 sT[128 * 72];  // [ch 0..127][s 0..63], stride 72 (16B-aligned rows)
  const int t = threadIdx.x;
  const int c0 = blockIdx.x * 64;   // 0..448 (first-half channel base)
  const int s0 = blockIdx.y * 64;
  const int b = blockIdx.z;
  const int sr = t >> 2;            // 0..63
  const int cq = (t & 3) * 16;      // 0/16/32/48
  const int s = s0 + sr;

  float c1[16], s1[16], c2[16], s2[16];
#pragma unroll
  for (int j = 0; j < 16; ++j) {
    const int i = c0 + cq + j;
    // invf = 10000^(-2i/1024) = exp2(-i * 2*log2(10000)/1024)
    const float invf = exp2f((float)i * -0.025952563241307517f);
    const float th = (float)s * invf;
    const float p1 = sinf(th), p2 = cosf(th);
    c1[j] = __cosf(p1); s1[j] = __sinf(p1);
    c2[j] = __cosf(p2); s2[j] = __sinf(p2);
  }

  const size_t base = ((size_t)(b * 1024 + s)) * 1024 + c0 + cq;

#pragma unroll
  for (int tz = 0; tz < 2; ++tz) {
    f16* ptr = tz ? k : q;
    f16x8 x1a = *(f16x8*)(ptr + base);
    f16x8 x1b = *(f16x8*)(ptr + base + 8);
    f16x8 x2a = *(f16x8*)(ptr + base + 512);
    f16x8 x2b = *(f16x8*)(ptr + base + 520);
    f16x8 r1a, r1b, r2a, r2b;
#pragma unroll
    for (int j = 0; j < 8; ++j) {
      float a0 = (float)x1a[j], b0 = (float)x2a[j];
      float a1 = (float)x1b[j], b1 = (float)x2b[j];
      r1a[j] = (f16)(a0 * c1[j] + b0 * s1[j]);
      r2a[j] = (f16)(b0 * c2[j] - a0 * s2[j]);
      r1b[j] = (f16)(a1 * c1[8 + j] + b1 * s1[8 + j]);
      r2b[j] = (f16)(b1 * c2[8 + j] - a1 * s2[8 + j]);
    }
    *(f16x8*)(ptr + base) = r1a;
    *(f16x8*)(ptr + base + 8) = r1b;
    *(f16x8*)(ptr + base + 512) = r2a;
    *(f16x8*)(ptr + base + 520) = r2b;
  }

  {  // V: rope then transpose into LDS
    f16x8 x1a = *(const f16x8*)(v + base);
    f16x8 x1b = *(const f16x8*)(v + base + 8);
    f16x8 x2a = *(const f16x8*)(v + base + 512);
    f16x8 x2b = *(const f16x8*)(v + base + 520);
#pragma unroll
    for (int j = 0; j < 8; ++j) {
      float a0 = (float)x1a[j], b0 = (float)x2a[j];
      float a1 = (float)x1b[j], b1 = (float)x2b[j];
      sT[(cq + j) * 72 + sr] = (f16)(a0 * c1[j] + b0 * s1[j]);
      sT[(64 + cq + j) * 72 + sr] = (f16)(b0 * c2[j] - a0 * s2[j]);
      sT[(cq + 8 + j) * 72 + sr] = (f16)(a1 * c1[8 + j] + b1 * s1[8 + j]);
      sT[(64 + cq + 8 + j) * 72 + sr] = (f16)(b1 * c2[8 + j] - a1 * s2[8 + j]);
    }
  }
  __syncthreads();

  // Write out: 128 ch-rows x 64 s, 2 threads per row, 64B contiguous each.
  const int lr = t >> 1;            // 0..127
  const int sh = (t & 1) * 32;
  const int h = (lr < 64) ? (c0 >> 6) : (8 + (c0 >> 6));
  const int d = lr & 63;
  const size_t gbase = ((size_t)((b * 16 + h) * 64 + d)) * 1024 + s0 + sh;
#pragma unroll
  for (int m = 0; m < 4; ++m)
    *(f16x8*)(vt + gbase + m * 8) = *(const f16x8*)(sT + lr * 72 + sh + m * 8);
}

// ---------------- Flash attention v3: transposed-score trick, no P roundtrip ------------
// Block = (b*h at blockIdx.x, q-tile 128 at blockIdx.y); S^T = K.Q^T so the exp2'd score
// C-layout IS the B-operand layout of mfma_16x16x16f16 -> PV straight from registers.
__global__ __launch_bounds__(256)
void attn_kernel(const f16* __restrict__ q, const f16* __restrict__ k,
                 const f16* __restrict__ vt, f16* __restrict__ xo) {
  __shared__ __align__(16) f16 sK[128 * 64];   // [k-row][d], XOR-8 chunk swizzle
  __shared__ __align__(16) f16 sV[64 * 128];   // [d][s], XOR-16 chunk swizzle
  const int tid = threadIdx.x;
  const int lane = tid & 63;
  const int wv = tid >> 6;
  const int l15 = lane & 15;
  const int quad = lane >> 4;
  const int bh = blockIdx.x;   // 0..127
  const int qt = blockIdx.y;   // 0..7
  const int b = bh >> 4, h = bh & 15;
  const size_t hidbase = ((size_t)b << 20) + (size_t)(h << 6);
  const int sq0 = qt * 128 + wv * 32;

  // Q fragments (row = lane&15 -> q-row, k consecutive), persistent in VGPRs.
  f16x8 fq[2][2];
#pragma unroll
  for (int mi = 0; mi < 2; ++mi)
#pragma unroll
    for (int kc = 0; kc < 2; ++kc)
      fq[mi][kc] = *(const f16x8*)(q + hidbase + (size_t)(sq0 + mi * 16 + l15) * 1024 +
                                   kc * 32 + quad * 8);

  f32x4 ot[2][4] = {};   // O^T [mi][nd]: col = q (lane&15), row = d (quad*4+r)
  float lrun[2] = {};    // per-lane partial row-sum for col q = lane&15

  const float SC = 0.18033688011112042f;  // log2(e) / sqrt(64)

  // K staging: lane -> row octet (lane>>3), chunk (lane&7)^(lane>>3).
  const int srowK = lane >> 3;
  const int schunkK = (lane & 7) ^ srowK;
  const f16* gK = k + hidbase + (size_t)(wv * 32 + srowK) * 1024 + schunkK * 8;
  // V staging: rows are d (256B each, 16 chunks). lane -> row (lane>>4), slot lane&15.
  const int vrow = lane >> 4;                   // 0..3
  const f16* gVbase = vt + ((size_t)bh * 64) * 1024;

  for (int kt = 0; kt < 8; ++kt) {
    const int sk0 = kt * 128;
    __syncthreads();  // all waves done reading sK/sV of previous tile
#pragma unroll
    for (int j = 0; j < 4; ++j)
      g2l16(sK + (wv * 32 + j * 8) * 64, gK + (size_t)(sk0 + j * 8) * 1024);
#pragma unroll
    for (int i = 0; i < 4; ++i) {
      const int row = wv * 16 + i * 4 + vrow;
      const int gch = (lane & 15) ^ (i * 4 + vrow);
      g2l16(sV + (wv * 16 + i * 4) * 128, gVbase + (size_t)row * 1024 + sk0 + gch * 8);
    }
    __syncthreads();  // staging drained

#pragma unroll
    for (int nj = 0; nj < 8; ++nj) {
      // --- S^T subtile (16 keys x 16 q) x 2 q-tiles: A = K-frag, B = Q-frag ---
      f32x4 st[2] = {};
#pragma unroll
      for (int kc = 0; kc < 2; ++kc) {
        f16x8 fk = *(const f16x8*)(sK + (nj * 16 + l15) * 64 +
                                   ((kc * 4 + quad) ^ (l15 & 7)) * 8);
        st[0] = MFMA16(fk, fq[0][kc], st[0]);
        st[1] = MFMA16(fk, fq[1][kc], st[1]);
      }
      // --- fixed-shift softmax, pack to P^T B-fragment in registers ---
      f16x4 pf[2];
#pragma unroll
      for (int mi = 0; mi < 2; ++mi) {
#pragma unroll
        for (int r = 0; r < 4; ++r) {
          float p = exp2f(fmaf(st[mi][r], SC, -12.0f));
          lrun[mi] += p;
          pf[mi][r] = (f16)p;
        }
      }
      // --- PV: O^T[d][q] += V^T-frag(A) * P^T-frag(B), K=16 MFMA ---
#pragma unroll
      for (int nd = 0; nd < 4; ++nd) {
        f16x4 fv = *(const f16x4*)(sV + (nd * 16 + l15) * 128 +
                                   ((nj * 2 + (quad >> 1)) ^ l15) * 8 + (quad & 1) * 4);
        ot[0][nd] = MFMA16K16(fv, pf[0], ot[0][nd]);
        ot[1][nd] = MFMA16K16(fv, pf[1], ot[1][nd]);
      }
    }
  }

  // Row sums: reduce per-lane partials across the 4 quads (cols live at lane&15).
  float inv[2];
#pragma unroll
  for (int mi = 0; mi < 2; ++mi) {
    float l = lrun[mi];
    l += __shfl_xor(l, 16, 64);
    l += __shfl_xor(l, 32, 64);
    inv[mi] = 1.0f / l;
  }

  // Epilogue: O^T -> per-wave LDS region (reusing sK) -> coalesced global stores.
  __syncthreads();  // all waves done with last tile's sK reads
  f16* sO = sK + wv * (32 * 72);  // [q_local 0..31][d 0..63], stride 72
#pragma unroll
  for (int mi = 0; mi < 2; ++mi)
#pragma unroll
    for (int nd = 0; nd < 4; ++nd) {
      f16x4 w;
#pragma unroll
      for (int r = 0; r < 4; ++r) w[r] = (f16)(ot[mi][nd][r] * inv[mi]);
      *(f16x4*)(sO + (mi * 16 + l15) * 72 + nd * 16 + quad * 4) = w;
    }
  // Per-wave in-order DS: writes above complete before these reads.
  const int orow = lane >> 1;          // 0..31
  const int ocol = (lane & 1) * 32;
  const size_t gb = hidbase + (size_t)(sq0 + orow) * 1024 + ocol;
#pragma unroll
  for (int m = 0; m < 4; ++m)
    *(f16x8*)(xo + gb + m * 8) = *(const f16x8*)(sO + orow * 72 + ocol + m * 8);
}

// ---------------- launch ----------------
extern "C" void kernel_launch(void* const* d_in, const int* in_sizes, int n_in,
                              void* d_out, int out_size, void* d_ws, size_t ws_size,
                              hipStream_t stream) {
  const float* query = (const float*)d_in[0];
  const float* key   = (const float*)d_in[1];
  const float* value = (const float*)d_in[2];
  const float* Wq = (const float*)d_in[3];
  const float* bq = (const float*)d_in[4];
  const float* Wk = (const float*)d_in[5];
  const float* bk = (const float*)d_in[6];
  const float* Wv = (const float*)d_in[7];
  const float* bv = (const float*)d_in[8];
  const float* Wo = (const float*)d_in[9];
  const float* bo = (const float*)d_in[10];

  char* ws = (char*)d_ws;
  const size_t SZT = (size_t)8 * 1024 * 1024 * 2;  // 16 MB per fp16 activation tensor
  const size_t SZW = (size_t)1024 * 1024 * 2;      // 2 MB per fp16 weight
  f16* Wqh = (f16*)(ws);
  f16* Wkh = (f16*)(ws + SZW);
  f16* Wvh = (f16*)(ws + 2 * SZW);
  f16* Woh = (f16*)(ws + 3 * SZW);
  f16* Qp  = (f16*)(ws + 4 * SZW);
  f16* Kp  = (f16*)(ws + 4 * SZW + SZT);
  f16* Vp  = (f16*)(ws + 4 * SZW + 2 * SZT);
  f16* Vt  = (f16*)(ws + 4 * SZW + 3 * SZT);
  f16* Xat = (f16*)(ws + 4 * SZW + 4 * SZT);
  // total ws use: 8 MB + 5*16 MB = 88 MB

  cvt4_kernel<<<dim3(1024, 4), 256, 0, stream>>>(Wq, Wk, Wv, Wo, Wqh, Wkh, Wvh, Woh);

  GemmBatch gqkv;
  gqkv.A[0] = query; gqkv.A[1] = key; gqkv.A[2] = value;
  gqkv.W[0] = Wqh;   gqkv.W[1] = Wkh; gqkv.W[2] = Wvh;
  gqkv.bias[0] = bq; gqkv.bias[1] = bk; gqkv.bias[2] = bv;
  gqkv.O[0] = Qp;    gqkv.O[1] = Kp;  gqkv.O[2] = Vp;
  gemm_f16_kernel<true, true><<<dim3(8, 64, 3), 256, 0, stream>>>(gqkv);

  rope_kernel<<<dim3(8, 16, 8), 256, 0, stream>>>(Qp, Kp, Vp, Vt);

  attn_kernel<<<dim3(128, 8), 256, 0, stream>>>(Qp, Kp, Vt, Xat);

  GemmBatch go;
  go.A[0] = Xat; go.A[1] = nullptr; go.A[2] = nullptr;
  go.W[0] = Woh; go.W[1] = nullptr; go.W[2] = nullptr;
  go.bias[0] = bo; go.bias[1] = nullptr; go.bias[2] = nullptr;
  go.O[0] = d_out; go.O[1] = nullptr; go.O[2] = nullptr;
  gemm_f16_kernel<false, false><<<dim3(8, 64, 1), 256, 0, stream>>>(go);
}

// Round 5
// 331.169 us; speedup vs baseline: 1.1276x; 1.1276x over previous
//
#include <hip/hip_runtime.h>
#include <hip/hip_fp16.h>
#include <cmath>

// Problem constants: B=8, S=1024, HID=1024, HEADS=16, HEAD_DIM=64
// M = B*S = 8192 rows for every GEMM; N = K = 1024.

typedef _Float16 f16;
typedef __attribute__((ext_vector_type(4))) _Float16 f16x4;
typedef __attribute__((ext_vector_type(8))) _Float16 f16x8;
typedef __attribute__((ext_vector_type(4))) float f32x4;

#define MFMA16(a, b, c) __builtin_amdgcn_mfma_f32_16x16x32_f16((a), (b), (c), 0, 0, 0)
#define MFMA16K16(a, b, c) __builtin_amdgcn_mfma_f32_16x16x16f16((a), (b), (c), 0, 0, 0)

// Async global->LDS, 16B per lane. LDS dest is wave-uniform base + lane*16.
__device__ __forceinline__ void g2l16(void* lds, const void* g) {
  __builtin_amdgcn_global_load_lds(
      (const __attribute__((address_space(1))) void*)g,
      (__attribute__((address_space(3))) void*)lds,
      16, 0, 0);
}

// ---------------- fp32 -> fp16 conversion kernels ----------------
__global__ void cvt3_kernel(const float* __restrict__ a, const float* __restrict__ b,
                            const float* __restrict__ c,
                            f16* __restrict__ oa, f16* __restrict__ ob, f16* __restrict__ oc) {
  const float* src;
  f16* dst;
  if (blockIdx.y == 0) { src = a; dst = oa; }
  else if (blockIdx.y == 1) { src = b; dst = ob; }
  else { src = c; dst = oc; }
  size_t t = (size_t)blockIdx.x * 256 + threadIdx.x;   // indexes float4 groups
  float4 v = ((const float4*)src)[t];
  f16x4 w = { (f16)v.x, (f16)v.y, (f16)v.z, (f16)v.w };
  ((f16x4*)dst)[t] = w;
}

__global__ void cvt4_kernel(const float* __restrict__ a, const float* __restrict__ b,
                            const float* __restrict__ c, const float* __restrict__ d,
                            f16* __restrict__ oa, f16* __restrict__ ob,
                            f16* __restrict__ oc, f16* __restrict__ od) {
  const float* src;
  f16* dst;
  if (blockIdx.y == 0) { src = a; dst = oa; }
  else if (blockIdx.y == 1) { src = b; dst = ob; }
  else if (blockIdx.y == 2) { src = c; dst = oc; }
  else { src = d; dst = od; }
  size_t t = (size_t)blockIdx.x * 256 + threadIdx.x;
  float4 v = ((const float4*)src)[t];
  f16x4 w = { (f16)v.x, (f16)v.y, (f16)v.z, (f16)v.w };
  ((f16x4*)dst)[t] = w;
}

// ---------------- GEMM: Out[M,N] = A[M,K] * W[N,K]^T + bias, fp16 MFMA ----------------
// 128x128 tile, BK=64, 4 waves (2x2 of 64x64), BOTH operands via global_load_lds + XOR
// chunk swizzle (pure async DMA staging — R4 showed replacing A's DMA with a
// load/cvt/ds_write chain is 2x latency-serialized; do NOT fuse conversion here).
// XCD-aware swizzle: flat%8 picks an m-slab (8 m-tiles), so each XCD's L2 reuses its A
// slab across all 8 n-tiles and A is fetched ~once from HBM instead of 8x
// (R4 verified: FETCH 200 -> 74 MB).
struct GemmBatch {
  const f16* A[3];
  const f16* W[3];
  const float* bias[3];
  void* O[3];
};

template <bool OUT_F16>
__global__ __launch_bounds__(256)
void gemm_f16_kernel(GemmBatch gb) {
  __shared__ __align__(16) f16 sA[128 * 64];
  __shared__ __align__(16) f16 sB[128 * 64];
  const int z = blockIdx.z;
  const f16* __restrict__ A = gb.A[z];
  const f16* __restrict__ Bw = gb.W[z];
  const float* __restrict__ bias = gb.bias[z];
  void* __restrict__ Out = gb.O[z];

  const int tid = threadIdx.x;
  const int lane = tid & 63;
  const int wv = tid >> 6;
  const int l15 = lane & 15;
  const int quad = lane >> 4;

  // XCD swizzle: grid (8,64,z); flat%8 = XCD (dispatch round-robin heuristic).
  const int flat = blockIdx.x + (blockIdx.y << 3);
  const int xcd = flat & 7;
  const int t64 = flat >> 3;               // 0..63
  const int m0 = (xcd * 8 + (t64 & 7)) * 128;
  const int n0 = (t64 >> 3) * 128;

  const int wm = (wv & 1) * 64;
  const int wn = (wv >> 1) * 64;

  // Staging: lane -> row octet (lane>>3), chunk (lane&7)^(lane>>3).
  const int srow = lane >> 3;
  const int schunk = (lane & 7) ^ srow;
  const f16* gA = A + (size_t)(m0 + wv * 32 + srow) * 1024 + schunk * 8;
  const f16* gB = Bw + (size_t)(n0 + wv * 32 + srow) * 1024 + schunk * 8;
  f16* lA = sA + (wv * 32) * 64;
  f16* lB = sB + (wv * 32) * 64;

  f32x4 acc[4][4] = {};

  for (int k0 = 0; k0 < 1024; k0 += 64) {
    __syncthreads();  // previous iter's LDS reads complete before overwrite
#pragma unroll
    for (int j = 0; j < 4; ++j) {
      g2l16(lA + j * 8 * 64, gA + (size_t)j * 8 * 1024 + k0);
      g2l16(lB + j * 8 * 64, gB + (size_t)j * 8 * 1024 + k0);
    }
    __syncthreads();  // staging drained (vmcnt(0) before barrier)
#pragma unroll
    for (int kc = 0; kc < 2; ++kc) {
      f16x8 af[4], bf[4];
#pragma unroll
      for (int t = 0; t < 4; ++t) {
        const int swz = ((kc * 4 + quad) ^ (l15 & 7)) * 8;
        af[t] = *(const f16x8*)(sA + (wm + t * 16 + l15) * 64 + swz);
        bf[t] = *(const f16x8*)(sB + (wn + t * 16 + l15) * 64 + swz);
      }
#pragma unroll
      for (int mi = 0; mi < 4; ++mi)
#pragma unroll
        for (int ni = 0; ni < 4; ++ni)
          acc[mi][ni] = MFMA16(af[mi], bf[ni], acc[mi][ni]);
    }
  }

  // Epilogue. C/D layout: row = quad*4 + r, col = lane&15 (per 16x16 tile).
#pragma unroll
  for (int ni = 0; ni < 4; ++ni) {
    const int col = n0 + wn + ni * 16 + l15;
    const float bv = bias[col];
#pragma unroll
    for (int mi = 0; mi < 4; ++mi) {
      const int row0 = m0 + wm + mi * 16 + quad * 4;
#pragma unroll
      for (int r = 0; r < 4; ++r) {
        float v = acc[mi][ni][r] + bv;
        if (OUT_F16)
          ((f16*)Out)[(size_t)(row0 + r) * 1024 + col] = (f16)v;
        else
          ((float*)Out)[(size_t)(row0 + r) * 1024 + col] = v;
      }
    }
  }
}

// ---------------- RoPE v2: fully coalesced, Vt transpose through LDS ----------------
__global__ __launch_bounds__(256)
void rope_kernel(f16* __restrict__ q, f16* __restrict__ k,
                 const f16* __restrict__ v, f16* __restrict__ vt) {
  __shared__ f16 sT[128 * 72];  // [ch 0..127][s 0..63], stride 72 (16B-aligned rows)
  const int t = threadIdx.x;
  const int c0 = blockIdx.x * 64;   // 0..448 (first-half channel base)
  const int s0 = blockIdx.y * 64;
  const int b = blockIdx.z;
  const int sr = t >> 2;            // 0..63
  const int cq = (t & 3) * 16;      // 0/16/32/48
  const int s = s0 + sr;

  float c1[16], s1[16], c2[16], s2[16];
#pragma unroll
  for (int j = 0; j < 16; ++j) {
    const int i = c0 + cq + j;
    // invf = 10000^(-2i/1024) = exp2(-i * 2*log2(10000)/1024)
    const float invf = exp2f((float)i * -0.025952563241307517f);
    const float th = (float)s * invf;
    const float p1 = sinf(th), p2 = cosf(th);
    c1[j] = __cosf(p1); s1[j] = __sinf(p1);
    c2[j] = __cosf(p2); s2[j] = __sinf(p2);
  }

  const size_t base = ((size_t)(b * 1024 + s)) * 1024 + c0 + cq;

#pragma unroll
  for (int tz = 0; tz < 2; ++tz) {
    f16* ptr = tz ? k : q;
    f16x8 x1a = *(f16x8*)(ptr + base);
    f16x8 x1b = *(f16x8*)(ptr + base + 8);
    f16x8 x2a = *(f16x8*)(ptr + base + 512);
    f16x8 x2b = *(f16x8*)(ptr + base + 520);
    f16x8 r1a, r1b, r2a, r2b;
#pragma unroll
    for (int j = 0; j < 8; ++j) {
      float a0 = (float)x1a[j], b0 = (float)x2a[j];
      float a1 = (float)x1b[j], b1 = (float)x2b[j];
      r1a[j] = (f16)(a0 * c1[j] + b0 * s1[j]);
      r2a[j] = (f16)(b0 * c2[j] - a0 * s2[j]);
      r1b[j] = (f16)(a1 * c1[8 + j] + b1 * s1[8 + j]);
      r2b[j] = (f16)(b1 * c2[8 + j] - a1 * s2[8 + j]);
    }
    *(f16x8*)(ptr + base) = r1a;
    *(f16x8*)(ptr + base + 8) = r1b;
    *(f16x8*)(ptr + base + 512) = r2a;
    *(f16x8*)(ptr + base + 520) = r2b;
  }

  {  // V: rope then transpose into LDS
    f16x8 x1a = *(const f16x8*)(v + base);
    f16x8 x1b = *(const f16x8*)(v + base + 8);
    f16x8 x2a = *(const f16x8*)(v + base + 512);
    f16x8 x2b = *(const f16x8*)(v + base + 520);
#pragma unroll
    for (int j = 0; j < 8; ++j) {
      float a0 = (float)x1a[j], b0 = (float)x2a[j];
      float a1 = (float)x1b[j], b1 = (float)x2b[j];
      sT[(cq + j) * 72 + sr] = (f16)(a0 * c1[j] + b0 * s1[j]);
      sT[(64 + cq + j) * 72 + sr] = (f16)(b0 * c2[j] - a0 * s2[j]);
      sT[(cq + 8 + j) * 72 + sr] = (f16)(a1 * c1[8 + j] + b1 * s1[8 + j]);
      sT[(64 + cq + 8 + j) * 72 + sr] = (f16)(b1 * c2[8 + j] - a1 * s2[8 + j]);
    }
  }
  __syncthreads();

  // Write out: 128 ch-rows x 64 s, 2 threads per row, 64B contiguous each.
  const int lr = t >> 1;            // 0..127
  const int sh = (t & 1) * 32;
  const int h = (lr < 64) ? (c0 >> 6) : (8 + (c0 >> 6));
  const int d = lr & 63;
  const size_t gbase = ((size_t)((b * 16 + h) * 64 + d)) * 1024 + s0 + sh;
#pragma unroll
  for (int m = 0; m < 4; ++m)
    *(f16x8*)(vt + gbase + m * 8) = *(const f16x8*)(sT + lr * 72 + sh + m * 8);
}

// ---------------- Flash attention v3: transposed-score trick, no P roundtrip ------------
// Block = (b*h at blockIdx.x, q-tile 128 at blockIdx.y); S^T = K.Q^T so the exp2'd score
// C-layout IS the B-operand layout of mfma_16x16x16f16 -> PV straight from registers.
__global__ __launch_bounds__(256)
void attn_kernel(const f16* __restrict__ q, const f16* __restrict__ k,
                 const f16* __restrict__ vt, f16* __restrict__ xo) {
  __shared__ __align__(16) f16 sK[128 * 64];   // [k-row][d], XOR-8 chunk swizzle
  __shared__ __align__(16) f16 sV[64 * 128];   // [d][s], XOR-16 chunk swizzle
  const int tid = threadIdx.x;
  const int lane = tid & 63;
  const int wv = tid >> 6;
  const int l15 = lane & 15;
  const int quad = lane >> 4;
  const int bh = blockIdx.x;   // 0..127
  const int qt = blockIdx.y;   // 0..7
  const int b = bh >> 4, h = bh & 15;
  const size_t hidbase = ((size_t)b << 20) + (size_t)(h << 6);
  const int sq0 = qt * 128 + wv * 32;

  // Q fragments (row = lane&15 -> q-row, k consecutive), persistent in VGPRs.
  f16x8 fq[2][2];
#pragma unroll
  for (int mi = 0; mi < 2; ++mi)
#pragma unroll
    for (int kc = 0; kc < 2; ++kc)
      fq[mi][kc] = *(const f16x8*)(q + hidbase + (size_t)(sq0 + mi * 16 + l15) * 1024 +
                                   kc * 32 + quad * 8);

  f32x4 ot[2][4] = {};   // O^T [mi][nd]: col = q (lane&15), row = d (quad*4+r)
  float lrun[2] = {};    // per-lane partial row-sum for col q = lane&15

  const float SC = 0.18033688011112042f;  // log2(e) / sqrt(64)

  // K staging: lane -> row octet (lane>>3), chunk (lane&7)^(lane>>3).
  const int srowK = lane >> 3;
  const int schunkK = (lane & 7) ^ srowK;
  const f16* gK = k + hidbase + (size_t)(wv * 32 + srowK) * 1024 + schunkK * 8;
  // V staging: rows are d (256B each, 16 chunks). lane -> row (lane>>4), slot lane&15.
  const int vrow = lane >> 4;                   // 0..3
  const f16* gVbase = vt + ((size_t)bh * 64) * 1024;

  for (int kt = 0; kt < 8; ++kt) {
    const int sk0 = kt * 128;
    __syncthreads();  // all waves done reading sK/sV of previous tile
#pragma unroll
    for (int j = 0; j < 4; ++j)
      g2l16(sK + (wv * 32 + j * 8) * 64, gK + (size_t)(sk0 + j * 8) * 1024);
#pragma unroll
    for (int i = 0; i < 4; ++i) {
      const int row = wv * 16 + i * 4 + vrow;
      const int gch = (lane & 15) ^ (i * 4 + vrow);
      g2l16(sV + (wv * 16 + i * 4) * 128, gVbase + (size_t)row * 1024 + sk0 + gch * 8);
    }
    __syncthreads();  // staging drained

#pragma unroll
    for (int nj = 0; nj < 8; ++nj) {
      // --- S^T subtile (16 keys x 16 q) x 2 q-tiles: A = K-frag, B = Q-frag ---
      f32x4 st[2] = {};
#pragma unroll
      for (int kc = 0; kc < 2; ++kc) {
        f16x8 fk = *(const f16x8*)(sK + (nj * 16 + l15) * 64 +
                                   ((kc * 4 + quad) ^ (l15 & 7)) * 8);
        st[0] = MFMA16(fk, fq[0][kc], st[0]);
        st[1] = MFMA16(fk, fq[1][kc], st[1]);
      }
      // --- fixed-shift softmax, pack to P^T B-fragment in registers ---
      f16x4 pf[2];
#pragma unroll
      for (int mi = 0; mi < 2; ++mi) {
#pragma unroll
        for (int r = 0; r < 4; ++r) {
          float p = exp2f(fmaf(st[mi][r], SC, -12.0f));
          lrun[mi] += p;
          pf[mi][r] = (f16)p;
        }
      }
      // --- PV: O^T[d][q] += V^T-frag(A) * P^T-frag(B), K=16 MFMA ---
#pragma unroll
      for (int nd = 0; nd < 4; ++nd) {
        f16x4 fv = *(const f16x4*)(sV + (nd * 16 + l15) * 128 +
                                   ((nj * 2 + (quad >> 1)) ^ l15) * 8 + (quad & 1) * 4);
        ot[0][nd] = MFMA16K16(fv, pf[0], ot[0][nd]);
        ot[1][nd] = MFMA16K16(fv, pf[1], ot[1][nd]);
      }
    }
  }

  // Row sums: reduce per-lane partials across the 4 quads (cols live at lane&15).
  float inv[2];
#pragma unroll
  for (int mi = 0; mi < 2; ++mi) {
    float l = lrun[mi];
    l += __shfl_xor(l, 16, 64);
    l += __shfl_xor(l, 32, 64);
    inv[mi] = 1.0f / l;
  }

  // Epilogue: O^T -> per-wave LDS region (reusing sK) -> coalesced global stores.
  __syncthreads();  // all waves done with last tile's sK reads
  f16* sO = sK + wv * (32 * 72);  // [q_local 0..31][d 0..63], stride 72
#pragma unroll
  for (int mi = 0; mi < 2; ++mi)
#pragma unroll
    for (int nd = 0; nd < 4; ++nd) {
      f16x4 w;
#pragma unroll
      for (int r = 0; r < 4; ++r) w[r] = (f16)(ot[mi][nd][r] * inv[mi]);
      *(f16x4*)(sO + (mi * 16 + l15) * 72 + nd * 16 + quad * 4) = w;
    }
  // Per-wave in-order DS: writes above complete before these reads.
  const int orow = lane >> 1;          // 0..31
  const int ocol = (lane & 1) * 32;
  const size_t gb = hidbase + (size_t)(sq0 + orow) * 1024 + ocol;
#pragma unroll
  for (int m = 0; m < 4; ++m)
    *(f16x8*)(xo + gb + m * 8) = *(const f16x8*)(sO + orow * 72 + ocol + m * 8);
}

// ---------------- launch ----------------
extern "C" void kernel_launch(void* const* d_in, const int* in_sizes, int n_in,
                              void* d_out, int out_size, void* d_ws, size_t ws_size,
                              hipStream_t stream) {
  const float* query = (const float*)d_in[0];
  const float* key   = (const float*)d_in[1];
  const float* value = (const float*)d_in[2];
  const float* Wq = (const float*)d_in[3];
  const float* bq = (const float*)d_in[4];
  const float* Wk = (const float*)d_in[5];
  const float* bk = (const float*)d_in[6];
  const float* Wv = (const float*)d_in[7];
  const float* bv = (const float*)d_in[8];
  const float* Wo = (const float*)d_in[9];
  const float* bo = (const float*)d_in[10];

  char* ws = (char*)d_ws;
  const size_t SZT = (size_t)8 * 1024 * 1024 * 2;  // 16 MB per fp16 activation tensor
  const size_t SZW = (size_t)1024 * 1024 * 2;      // 2 MB per fp16 weight
  f16* Xq  = (f16*)(ws);
  f16* Xk  = (f16*)(ws + SZT);
  f16* Xv  = (f16*)(ws + 2 * SZT);
  f16* Wqh = (f16*)(ws + 3 * SZT);
  f16* Wkh = (f16*)(ws + 3 * SZT + SZW);
  f16* Wvh = (f16*)(ws + 3 * SZT + 2 * SZW);
  f16* Woh = (f16*)(ws + 3 * SZT + 3 * SZW);
  f16* Qp  = (f16*)(ws + 3 * SZT + 4 * SZW);
  f16* Kp  = (f16*)(ws + 4 * SZT + 4 * SZW);
  f16* Vp  = (f16*)(ws + 5 * SZT + 4 * SZW);
  f16* Vt  = (f16*)(ws + 6 * SZT + 4 * SZW);
  f16* Xat = (f16*)(ws + 7 * SZT + 4 * SZW);
  // total ws use: 8*16MB + 8MB = 136 MB

  cvt3_kernel<<<dim3(8192, 3), 256, 0, stream>>>(query, key, value, Xq, Xk, Xv);
  cvt4_kernel<<<dim3(1024, 4), 256, 0, stream>>>(Wq, Wk, Wv, Wo, Wqh, Wkh, Wvh, Woh);

  GemmBatch gqkv;
  gqkv.A[0] = Xq;  gqkv.A[1] = Xk;  gqkv.A[2] = Xv;
  gqkv.W[0] = Wqh; gqkv.W[1] = Wkh; gqkv.W[2] = Wvh;
  gqkv.bias[0] = bq; gqkv.bias[1] = bk; gqkv.bias[2] = bv;
  gqkv.O[0] = Qp;  gqkv.O[1] = Kp;  gqkv.O[2] = Vp;
  gemm_f16_kernel<true><<<dim3(8, 64, 3), 256, 0, stream>>>(gqkv);

  rope_kernel<<<dim3(8, 16, 8), 256, 0, stream>>>(Qp, Kp, Vp, Vt);

  attn_kernel<<<dim3(128, 8), 256, 0, stream>>>(Qp, Kp, Vt, Xat);

  GemmBatch go;
  go.A[0] = Xat; go.A[1] = nullptr; go.A[2] = nullptr;
  go.W[0] = Woh; go.W[1] = nullptr; go.W[2] = nullptr;
  go.bias[0] = bo; go.bias[1] = nullptr; go.bias[2] = nullptr;
  go.O[0] = d_out; go.O[1] = nullptr; go.O[2] = nullptr;
  gemm_f16_kernel<false><<<dim3(8, 64, 1), 256, 0, stream>>>(go);
}